// Round 2
// baseline (9200.702 us; speedup 1.0000x reference)
//
#include <hip/hip_runtime.h>
#include <hip/hip_cooperative_groups.h>

#define PNUM 4354   // true P
#define KP   4416   // padded P (69 WGs * 64 cols; multiple of 64)
#define BATCH 32
#define SEQ  64
#define NWG  69
#define NTHR 512

typedef __attribute__((ext_vector_type(8))) _Float16 f16x8;
typedef __attribute__((ext_vector_type(4))) float f32x4;

__device__ __forceinline__ float silu_f(float x) { return x / (1.f + __expf(-x)); }

// ---- prep: Eh/El = fp16 split of (A - I) padded; theta fp32 + fp16 split; Bpad ----
__global__ void wsm_prep(const float* __restrict__ A, const float* __restrict__ Bv,
                         const float* __restrict__ th0,
                         _Float16* __restrict__ Eh, _Float16* __restrict__ El,
                         float* __restrict__ thf0, _Float16* __restrict__ thh0,
                         _Float16* __restrict__ thl0, float* __restrict__ Bpad) {
  const long long gsz = (long long)gridDim.x * blockDim.x;
  const long long gid = (long long)blockIdx.x * blockDim.x + threadIdx.x;
  const long long tot = (long long)KP * KP;
  for (long long i = gid; i < tot; i += gsz) {
    const int p = (int)(i / KP);
    const int q = (int)(i - (long long)p * KP);
    float v = 0.f;
    if (p < PNUM && q < PNUM) {
      v = A[(long long)p * PNUM + q];
      if (p == q) v -= 1.f;
    }
    const _Float16 h = (_Float16)v;
    Eh[i] = h;
    El[i] = (_Float16)(v - (float)h);
  }
  for (long long i = gid; i < KP; i += gsz)
    Bpad[i] = (i < PNUM) ? Bv[i] : 0.f;
  for (long long i = gid; i < (long long)BATCH * KP; i += gsz) {
    const int p = (int)(i % KP);
    const float v = (p < PNUM) ? th0[p] : 0.f;
    thf0[i] = v;
    const _Float16 h = (_Float16)v;
    thh0[i] = h;
    thl0[i] = (_Float16)(v - (float)h);
  }
}

// ---- MLP for batch row wg (wg<32), lanes 0..31 of wave 0, fp32 weights ----
__device__ void mlp_eval(int wg, int tid, const float* __restrict__ th_base,
                         float tin, float* __restrict__ musig) {
  if (wg < BATCH && tid < 32) {
    const float* th = th_base + (long long)wg * KP;
    const int o = tid;
    float h = silu_f(tin * th[o] + th[32 + o]);          // layer 0: 1->32
    int idx = 64;
    #pragma unroll
    for (int L = 0; L < 4; ++L) {                        // layers 1..4: 32->32
      const float* Wr = th + idx + o * 32;
      float hn = th[idx + 1024 + o];
      #pragma unroll
      for (int i = 0; i < 32; ++i)
        hn = fmaf(__shfl(h, i, 32), Wr[i], hn);
      h = silu_f(hn);
      idx += 1056;
    }
    float p0 = h * th[4288 + o];                          // final: 32->2
    float p1 = h * th[4320 + o];
    #pragma unroll
    for (int off = 16; off > 0; off >>= 1) {
      p0 += __shfl_xor(p0, off, 32);
      p1 += __shfl_xor(p1, off, 32);
    }
    if (o == 0) {
      musig[2 * wg] = tanhf(p0 + th[4352]);
      float lv = p1 + th[4353];
      lv = fminf(fmaxf(lv, -4.f), 4.f);
      musig[2 * wg + 1] = __expf(0.5f * lv);
    }
  }
}

// ---- main cooperative kernel: 64 sequential steps ----
__global__ void __launch_bounds__(NTHR) wsm_main(
    const float* __restrict__ xs, const float* __restrict__ noise,
    const int* __restrict__ inf_ptr,
    const _Float16* __restrict__ Eh, const _Float16* __restrict__ El,
    float* __restrict__ thf, _Float16* __restrict__ thh, _Float16* __restrict__ thl,
    const float* __restrict__ Bpad, float* __restrict__ musig,
    float* __restrict__ outp)
{
  cooperative_groups::grid_group grid = cooperative_groups::this_grid();
  const int tid = threadIdx.x;
  const int wg = blockIdx.x;
  const int wave = tid >> 6;
  const int lane = tid & 63;
  __shared__ float xprev_s[BATCH];
  __shared__ float delta_s[BATCH];
  if (tid < BATCH) xprev_s[tid] = 0.f;
  const int inf_start = *inf_ptr;

  mlp_eval(wg, tid, thf, 0.f, musig);   // mu_sigma0
  grid.sync();

  const int mr = lane & 15;            // A row (batch sub) / B col (p sub) / C col
  const int kg = lane >> 4;            // k-group
  const int pt = wave & 3;             // p-tile within WG
  const int bh = wave >> 2;            // batch half
  const int bbase = bh * 16;
  const int pc = wg * 64 + pt * 16 + mr;
  const _Float16* const Ehrow = Eh + (long long)pc * KP + kg * 8;
  const _Float16* const Elrow = El + (long long)pc * KP + kg * 8;
  const int throw_off = (bbase + mr) * KP + kg * 8;

  for (int t = 0; t < SEQ; ++t) {
    const int inb = t & 1;
    const long long inoff = (long long)inb * BATCH * KP;
    const long long outoff = (long long)(inb ^ 1) * BATCH * KP;
    const float* thf_in = thf + inoff;
    float* thf_out = thf + outoff;
    _Float16* thh_out = thh + outoff;
    _Float16* thl_out = thl + outoff;

    if (tid < BATCH) {
      const int b = tid;
      const float mean = musig[2 * b];
      const float sd = musig[2 * b + 1];
      const float xhat = fmaf(noise[t * BATCH + b], sd, mean);
      const float xt = (t < inf_start) ? xs[b * SEQ + t] : xhat;
      delta_s[b] = xt - xprev_s[b];
      xprev_s[b] = xt;
      if (wg == 0) {
        outp[b * SEQ + t] = mean;
        outp[BATCH * SEQ + b * SEQ + t] = sd;
      }
    }
    __syncthreads();

    // acc = th_h*Eh^T + th_h*El^T + th_l*Eh^T   (fp32-class precision)
    const _Float16* ah_p = thh + inoff + throw_off;
    const _Float16* al_p = thl + inoff + throw_off;
    f32x4 hh0 = {0.f, 0.f, 0.f, 0.f};
    f32x4 hh1 = hh0, hl0 = hh0, hl1 = hh0, lh0 = hh0, lh1 = hh0;
    for (int k = 0; k < KP; k += 64) {   // 69 iters
      const f16x8 ah0 = *(const f16x8*)(ah_p + k);
      const f16x8 ah1 = *(const f16x8*)(ah_p + k + 32);
      const f16x8 al0 = *(const f16x8*)(al_p + k);
      const f16x8 al1 = *(const f16x8*)(al_p + k + 32);
      const f16x8 eh0 = *(const f16x8*)(Ehrow + k);
      const f16x8 eh1 = *(const f16x8*)(Ehrow + k + 32);
      const f16x8 el0 = *(const f16x8*)(Elrow + k);
      const f16x8 el1 = *(const f16x8*)(Elrow + k + 32);
      hh0 = __builtin_amdgcn_mfma_f32_16x16x32_f16(ah0, eh0, hh0, 0, 0, 0);
      hh1 = __builtin_amdgcn_mfma_f32_16x16x32_f16(ah1, eh1, hh1, 0, 0, 0);
      hl0 = __builtin_amdgcn_mfma_f32_16x16x32_f16(ah0, el0, hl0, 0, 0, 0);
      hl1 = __builtin_amdgcn_mfma_f32_16x16x32_f16(ah1, el1, hl1, 0, 0, 0);
      lh0 = __builtin_amdgcn_mfma_f32_16x16x32_f16(al0, eh0, lh0, 0, 0, 0);
      lh1 = __builtin_amdgcn_mfma_f32_16x16x32_f16(al1, eh1, lh1, 0, 0, 0);
    }
    const f32x4 acc = hh0 + hh1 + hl0 + hl1 + lh0 + lh1;

    const float bv = Bpad[pc];
    #pragma unroll
    for (int r = 0; r < 4; ++r) {
      const int m = bbase + kg * 4 + r;     // C/D row = batch index
      const long long idx = (long long)m * KP + pc;
      float v = thf_in[idx] + acc[r] + delta_s[m] * bv;
      v = fminf(fmaxf(v, -1.f), 1.f);
      thf_out[idx] = v;
      const _Float16 h = (_Float16)v;
      thh_out[idx] = h;
      thl_out[idx] = (_Float16)(v - (float)h);
    }

    grid.sync();
    mlp_eval(wg, tid, thf_out, (float)(t + 1) * (1.f / SEQ), musig);
    grid.sync();
  }
}

extern "C" void kernel_launch(void* const* d_in, const int* in_sizes, int n_in,
                              void* d_out, int out_size, void* d_ws, size_t ws_size,
                              hipStream_t stream) {
  const float* xs = (const float*)d_in[0];
  const float* noise = (const float*)d_in[1];
  const float* th0 = (const float*)d_in[2];
  const float* A = (const float*)d_in[3];
  const float* Bv = (const float*)d_in[4];
  const int* infs = (const int*)d_in[5];

  char* ws = (char*)d_ws;
  size_t off = 0;
  auto carve = [&](size_t bytes) -> void* {
    off = (off + 255) & ~(size_t)255;
    void* p = ws + off;
    off += bytes;
    return p;
  };
  _Float16* Eh = (_Float16*)carve((size_t)KP * KP * sizeof(_Float16));
  _Float16* El = (_Float16*)carve((size_t)KP * KP * sizeof(_Float16));
  float* thf = (float*)carve((size_t)2 * BATCH * KP * sizeof(float));
  _Float16* thh = (_Float16*)carve((size_t)2 * BATCH * KP * sizeof(_Float16));
  _Float16* thl = (_Float16*)carve((size_t)2 * BATCH * KP * sizeof(_Float16));
  float* Bpad = (float*)carve((size_t)KP * sizeof(float));
  float* musig = (float*)carve((size_t)BATCH * 2 * sizeof(float));
  float* outp = (float*)d_out;

  wsm_prep<<<dim3(1024), dim3(256), 0, stream>>>(A, Bv, th0, Eh, El, thf, thh, thl, Bpad);

  void* args[] = {(void*)&xs, (void*)&noise, (void*)&infs, (void*)&Eh, (void*)&El,
                  (void*)&thf, (void*)&thh, (void*)&thl, (void*)&Bpad,
                  (void*)&musig, (void*)&outp};
  hipLaunchCooperativeKernel((const void*)wsm_main, dim3(NWG), dim3(NTHR), args, 0, stream);
}

// Round 3
// 4500.683 us; speedup vs baseline: 2.0443x; 2.0443x over previous
//
#include <hip/hip_runtime.h>
#include <hip/hip_cooperative_groups.h>

#define PNUM 4354            // true P
#define PPAD 4416            // 276 * 16  (output/p padding)
#define KPAD 4608            // 144 * 32  (k padding; 4 chunks * 36 iters)
#define NPT  276             // p-tiles of 16
#define KITER 144            // k-iters of 32
#define NWG  138             // 1 block/CU (<=256), WG owns 32 p-cols
#define NTHR 512
#define THSTRIDE (32 * KPAD) // one theta buffer (elements)

typedef __attribute__((ext_vector_type(8))) _Float16 f16x8;
typedef __attribute__((ext_vector_type(4))) float f32x4;

#define MFMA16 __builtin_amdgcn_mfma_f32_16x16x32_f16

__device__ __forceinline__ float silu_f(float x) { return x / (1.f + __expf(-x)); }

// ---- prep: swizzled fp16-split E, theta fp32+fp16-split (both buffers), Bpad, flag ----
// E_swz[pt][ki][lane][j] = E[pt*16 + (lane&15)][ki*32 + (lane>>4)*8 + j]
__global__ void wsm_prep(const float* __restrict__ A, const float* __restrict__ Bv,
                         const float* __restrict__ th0,
                         _Float16* __restrict__ Ehs, _Float16* __restrict__ Els,
                         float* __restrict__ thf, _Float16* __restrict__ thh,
                         _Float16* __restrict__ thl, float* __restrict__ Bpad,
                         unsigned int* __restrict__ flag) {
  const long long gsz = (long long)gridDim.x * blockDim.x;
  const long long gid = (long long)blockIdx.x * blockDim.x + threadIdx.x;
  const long long totE = (long long)NPT * KITER * 64 * 8;
  for (long long i = gid; i < totE; i += gsz) {
    const int j    = (int)(i & 7);
    const int lane = (int)((i >> 3) & 63);
    const int ki   = (int)((i >> 9) % KITER);
    const int pt   = (int)(i / ((long long)KITER * 512));
    const int p = pt * 16 + (lane & 15);
    const int k = ki * 32 + ((lane >> 4) << 3) + j;
    float v = 0.f;
    if (p < PNUM && k < PNUM) {
      v = A[(long long)p * PNUM + k];
      if (p == k) v -= 1.f;
    }
    const _Float16 h = (_Float16)v;
    Ehs[i] = h;
    Els[i] = (_Float16)(v - (float)h);
  }
  for (long long i = gid; i < 2LL * THSTRIDE; i += gsz) {
    const int p = (int)(i % KPAD);
    const float v = (i < THSTRIDE && p < PNUM) ? th0[p] : 0.f;  // buf1 = zero (pads stay 0 forever)
    thf[i] = v;
    const _Float16 h = (_Float16)v;
    thh[i] = h;
    thl[i] = (_Float16)(v - (float)h);
  }
  for (long long i = gid; i < PPAD; i += gsz)
    Bpad[i] = (i < PNUM) ? Bv[i] : 0.f;
  if (gid == 0) *flag = 0u;
}

// ---- MLP for batch row b, lanes o=0..31, fp32 weights; publishes musig + release flag ----
__device__ __forceinline__ void mlp_eval(int b, int o, const float* __restrict__ th,
                                         float tin, float* __restrict__ musig,
                                         unsigned int* __restrict__ flag) {
  float h = silu_f(tin * th[o] + th[32 + o]);            // layer 0: 1->32
  int idx = 64;
  #pragma unroll
  for (int L = 0; L < 4; ++L) {                          // layers 1..4: 32->32
    const float* Wr = th + idx + o * 32;
    float hn = th[idx + 1024 + o];
    #pragma unroll
    for (int i = 0; i < 32; ++i)
      hn = fmaf(__shfl(h, i, 32), Wr[i], hn);
    h = silu_f(hn);
    idx += 1056;
  }
  float p0 = h * th[4288 + o];                           // final: 32->2
  float p1 = h * th[4320 + o];
  #pragma unroll
  for (int off = 16; off > 0; off >>= 1) {
    p0 += __shfl_xor(p0, off, 32);
    p1 += __shfl_xor(p1, off, 32);
  }
  if (o == 0) {
    const float mean = tanhf(p0 + th[4352]);
    float lv = p1 + th[4353];
    lv = fminf(fmaxf(lv, -4.f), 4.f);
    const float sd = __expf(0.5f * lv);
    __hip_atomic_store(&musig[2 * b], mean, __ATOMIC_RELAXED, __HIP_MEMORY_SCOPE_AGENT);
    __hip_atomic_store(&musig[2 * b + 1], sd, __ATOMIC_RELAXED, __HIP_MEMORY_SCOPE_AGENT);
    __hip_atomic_fetch_add(flag, 1u, __ATOMIC_RELEASE, __HIP_MEMORY_SCOPE_AGENT);
  }
}

// ---- main cooperative kernel: 64 sequential steps, 1 grid.sync/step ----
__global__ void __launch_bounds__(NTHR) wsm_main(
    const float* __restrict__ xs, const float* __restrict__ noise,
    const int* __restrict__ infp,
    const _Float16* __restrict__ Ehs, const _Float16* __restrict__ Els,
    float* __restrict__ thf, _Float16* __restrict__ thh, _Float16* __restrict__ thl,
    const float* __restrict__ Bpad, float* __restrict__ musig,
    unsigned int* __restrict__ flag, float* __restrict__ outp)
{
  cooperative_groups::grid_group grid = cooperative_groups::this_grid();
  const int tid = threadIdx.x;
  const int wg = blockIdx.x;
  const int wave = tid >> 6;
  const int lane = tid & 63;
  // GEMM geometry: wave = (kchunk<<1) | psub ; 36 k-iters per chunk
  const int psub = wave & 1;
  const int kc = wave >> 1;
  const long long ebase = (((long long)(wg * 2 + psub) * KITER + kc * 36) * 64 + lane) * 8;
  const int koff = kc * 1152 + ((lane >> 4) << 3);
  const int row0 = (lane & 15) * KPAD + koff;        // batch rows 0..15
  const int row1 = row0 + 16 * KPAD;                 // batch rows 16..31
  // epilogue geometry: thread -> (m, 2 consecutive p-cols)
  const int em = tid >> 4;
  const int epc0 = (tid & 15) * 2;
  const int inf_start = *infp;
  float xprev = 0.f;
  __shared__ float red[8][64][8];

  for (int t = 0; t < 64; ++t) {
    const int inb = t & 1;
    const float*    thf_in  = thf + inb * THSTRIDE;
    float*          thf_out = thf + (inb ^ 1) * THSTRIDE;
    const _Float16* thh_in  = thh + inb * THSTRIDE;
    _Float16*       thh_out = thh + (inb ^ 1) * THSTRIDE;
    const _Float16* thl_in  = thl + inb * THSTRIDE;
    _Float16*       thl_out = thl + (inb ^ 1) * THSTRIDE;

    // overlapped MLP(theta_t) on WGs 0..31 (wave 0, lanes<32)
    if (wg < 32 && wave == 0 && lane < 32)
      mlp_eval(wg, lane, thf_in + wg * KPAD, (float)t * (1.f / 64.f), musig, flag);

    // GEMM partial: acc[m][p] over this wave's k-chunk
    f32x4 z = {0.f, 0.f, 0.f, 0.f};
    f32x4 hh0 = z, hh1 = z, hl0 = z, hl1 = z, lh0 = z, lh1 = z;
    const _Float16* ehp  = Ehs + ebase;
    const _Float16* elp  = Els + ebase;
    const _Float16* ah0p = thh_in + row0;
    const _Float16* ah1p = thh_in + row1;
    const _Float16* al0p = thl_in + row0;
    const _Float16* al1p = thl_in + row1;
    #pragma unroll 4
    for (int i = 0; i < 36; ++i) {
      const f16x8 eh  = *(const f16x8*)(ehp + i * 512);
      const f16x8 el  = *(const f16x8*)(elp + i * 512);
      const f16x8 ah0 = *(const f16x8*)(ah0p + i * 32);
      const f16x8 ah1 = *(const f16x8*)(ah1p + i * 32);
      const f16x8 al0 = *(const f16x8*)(al0p + i * 32);
      const f16x8 al1 = *(const f16x8*)(al1p + i * 32);
      hh0 = MFMA16(ah0, eh, hh0, 0, 0, 0);
      hh1 = MFMA16(ah1, eh, hh1, 0, 0, 0);
      hl0 = MFMA16(ah0, el, hl0, 0, 0, 0);
      hl1 = MFMA16(ah1, el, hl1, 0, 0, 0);
      lh0 = MFMA16(al0, eh, lh0, 0, 0, 0);
      lh1 = MFMA16(al1, eh, lh1, 0, 0, 0);
    }
    const f32x4 c0 = hh0 + hl0 + lh0;   // batch rows 0..15
    const f32x4 c1 = hh1 + hl1 + lh1;   // batch rows 16..31
    #pragma unroll
    for (int r = 0; r < 4; ++r) {
      red[wave][lane][r] = c0[r];
      red[wave][lane][4 + r] = c1[r];
    }
    __syncthreads();

    // wait musig_t (32 producers/step, monotonic counter)
    const unsigned int tgt = 32u * (unsigned)(t + 1);
    while (__hip_atomic_load(flag, __ATOMIC_ACQUIRE, __HIP_MEMORY_SCOPE_AGENT) < tgt)
      __builtin_amdgcn_s_sleep(8);

    const float mean = __hip_atomic_load(&musig[2 * em], __ATOMIC_RELAXED, __HIP_MEMORY_SCOPE_AGENT);
    const float sd   = __hip_atomic_load(&musig[2 * em + 1], __ATOMIC_RELAXED, __HIP_MEMORY_SCOPE_AGENT);
    const float xhat = fmaf(noise[t * 32 + em], sd, mean);
    const float xt   = (t < inf_start) ? xs[em * 64 + t] : xhat;
    const float dlt  = xt - xprev;
    xprev = xt;

    // epilogue: 2 elements per thread: theta_{t+1}[em][pc], pc = wg*32 + epc0 + {0,1}
    #pragma unroll
    for (int jj = 0; jj < 2; ++jj) {
      const int pcl = epc0 + jj;
      const int pc = wg * 32 + pcl;
      const int lanei = (pcl & 15) + (((em & 15) >> 2) << 4);
      const int reg = (em & 15) & 3;
      const int hf4 = (em >> 4) * 4;
      float s = 0.f;
      #pragma unroll
      for (int k2 = 0; k2 < 4; ++k2)
        s += red[k2 * 2 + (pcl >> 4)][lanei][hf4 + reg];
      const long long idx = (long long)em * KPAD + pc;
      float v = thf_in[idx] + s + dlt * Bpad[pc];
      v = fminf(fmaxf(v, -1.f), 1.f);
      thf_out[idx] = v;
      const _Float16 hv = (_Float16)v;
      thh_out[idx] = hv;
      thl_out[idx] = (_Float16)(v - (float)hv);
    }

    if (wg == 0 && tid < 32) {
      outp[tid * 64 + t] = __hip_atomic_load(&musig[2 * tid], __ATOMIC_RELAXED, __HIP_MEMORY_SCOPE_AGENT);
      outp[32 * 64 + tid * 64 + t] = __hip_atomic_load(&musig[2 * tid + 1], __ATOMIC_RELAXED, __HIP_MEMORY_SCOPE_AGENT);
    }

    grid.sync();   // theta_{t+1} visible everywhere; musig consumed before next overwrite
  }
}

extern "C" void kernel_launch(void* const* d_in, const int* in_sizes, int n_in,
                              void* d_out, int out_size, void* d_ws, size_t ws_size,
                              hipStream_t stream) {
  const float* xs  = (const float*)d_in[0];
  const float* noise = (const float*)d_in[1];
  const float* th0 = (const float*)d_in[2];
  const float* A   = (const float*)d_in[3];
  const float* Bv  = (const float*)d_in[4];
  const int* infs  = (const int*)d_in[5];

  char* ws = (char*)d_ws;
  size_t off = 0;
  auto carve = [&](size_t bytes) -> void* {
    off = (off + 255) & ~(size_t)255;
    void* p = ws + off;
    off += bytes;
    return p;
  };
  _Float16* Ehs = (_Float16*)carve((size_t)NPT * KITER * 512 * sizeof(_Float16));
  _Float16* Els = (_Float16*)carve((size_t)NPT * KITER * 512 * sizeof(_Float16));
  float*    thf = (float*)carve((size_t)2 * THSTRIDE * sizeof(float));
  _Float16* thh = (_Float16*)carve((size_t)2 * THSTRIDE * sizeof(_Float16));
  _Float16* thl = (_Float16*)carve((size_t)2 * THSTRIDE * sizeof(_Float16));
  float*   Bpad = (float*)carve((size_t)PPAD * sizeof(float));
  float*  musig = (float*)carve((size_t)64 * sizeof(float));
  unsigned int* flag = (unsigned int*)carve(sizeof(unsigned int));
  float* outp = (float*)d_out;

  wsm_prep<<<dim3(1024), dim3(256), 0, stream>>>(A, Bv, th0, Ehs, Els, thf, thh, thl, Bpad, flag);

  void* args[] = {(void*)&xs, (void*)&noise, (void*)&infs, (void*)&Ehs, (void*)&Els,
                  (void*)&thf, (void*)&thh, (void*)&thl, (void*)&Bpad,
                  (void*)&musig, (void*)&flag, (void*)&outp};
  hipLaunchCooperativeKernel((const void*)wsm_main, dim3(NWG), dim3(NTHR), args, 0, stream);
}

// Round 4
// 4422.151 us; speedup vs baseline: 2.0806x; 1.0178x over previous
//
#include <hip/hip_runtime.h>
#include <hip/hip_cooperative_groups.h>

#define PNUM 4354            // true P
#define PPAD 4416            // 276 * 16  (output/p padding)
#define KPAD 4608            // 144 * 32  (k padding; 4 chunks * 36 iters)
#define NPT  276             // p-tiles of 16
#define KITER 144            // k-iters of 32
#define NWG  138             // 1 block/CU, WG owns 32 p-cols (2 tiles)
#define NTHR 512
#define HALFSTRIDE (144 * 512)        // one batch-half of swizzled theta (elems)
#define THSWZ (2 * HALFSTRIDE)        // one time-buffer of swizzled theta
#define THF_STRIDE (32 * KPAD)        // one time-buffer of row-major fp32 theta

typedef __attribute__((ext_vector_type(8))) _Float16 f16x8;
typedef __attribute__((ext_vector_type(4))) float f32x4;

#define MFMA16 __builtin_amdgcn_mfma_f32_16x16x32_f16

__device__ __forceinline__ float silu_f(float x) { return x / (1.f + __expf(-x)); }

// ---------------- prep ----------------
// E_swz[pt][ki][lane][j] = E[pt*16 + (lane&15)][ki*32 + (lane>>4)*8 + j]
// th_swz[tb][half][ki][lane][j] = theta[tb][half*16 + (lane&15)][ki*32 + ((lane>>4)&3)*8 + j]
__global__ void wsm_prep(const float* __restrict__ A, const float* __restrict__ Bv,
                         const float* __restrict__ th0,
                         _Float16* __restrict__ Ehs, _Float16* __restrict__ Els,
                         float* __restrict__ thf, _Float16* __restrict__ thh,
                         _Float16* __restrict__ thl, float* __restrict__ Bpad,
                         unsigned int* __restrict__ flag) {
  const long long gsz = (long long)gridDim.x * blockDim.x;
  const long long gid = (long long)blockIdx.x * blockDim.x + threadIdx.x;
  const long long totE8 = (long long)NPT * KITER * 64;     // f16x8 units
  for (long long u = gid; u < totE8; u += gsz) {
    const int lane = (int)(u & 63);
    const long long r = u >> 6;
    const int ki = (int)(r % KITER);
    const int pt = (int)(r / KITER);
    const int p = pt * 16 + (lane & 15);
    const int k0 = ki * 32 + ((lane >> 4) << 3);
    f16x8 h8, l8;
    #pragma unroll
    for (int j = 0; j < 8; ++j) {
      const int k = k0 + j;
      float v = 0.f;
      if (p < PNUM && k < PNUM) {
        v = A[(long long)p * PNUM + k];
        if (p == k) v -= 1.f;
      }
      const _Float16 h = (_Float16)v;
      h8[j] = h;
      l8[j] = (_Float16)(v - (float)h);
    }
    *(f16x8*)(Ehs + u * 8) = h8;
    *(f16x8*)(Els + u * 8) = l8;
  }
  // swizzled theta (both time buffers; buf1 zero so pads stay zero forever)
  for (long long i = gid; i < 2LL * THSWZ; i += gsz) {
    const long long local = i % THSWZ;
    const int tb = (int)(i / THSWZ);
    const int j = (int)(local & 7);
    const int lane = (int)((local >> 3) & 63);
    const int ki = (int)((local >> 9) % KITER);
    const int Pc = ki * 32 + (((lane >> 4) & 3) << 3) + j;
    const float v = (tb == 0 && Pc < PNUM) ? th0[Pc] : 0.f;
    const _Float16 h = (_Float16)v;
    thh[i] = h;
    thl[i] = (_Float16)(v - (float)h);
  }
  // row-major fp32 theta (for MLP + epilogue base)
  for (long long i = gid; i < 2LL * THF_STRIDE; i += gsz) {
    const int p = (int)(i % KPAD);
    thf[i] = (i < THF_STRIDE && p < PNUM) ? th0[p] : 0.f;
  }
  for (long long i = gid; i < PPAD; i += gsz)
    Bpad[i] = (i < PNUM) ? Bv[i] : 0.f;
  if (gid == 0) *flag = 0u;
}

// ---- MLP for batch row b, lanes o=0..31, fp32 weights; publishes musig + release flag ----
__device__ __forceinline__ void mlp_eval(int b, int o, const float* __restrict__ th,
                                         float tin, float* __restrict__ musig,
                                         unsigned int* __restrict__ flag) {
  float h = silu_f(tin * th[o] + th[32 + o]);            // layer 0: 1->32
  int idx = 64;
  #pragma unroll
  for (int L = 0; L < 4; ++L) {                          // layers 1..4: 32->32
    const float* Wr = th + idx + o * 32;
    float hn = th[idx + 1024 + o];
    #pragma unroll
    for (int i = 0; i < 32; ++i)
      hn = fmaf(__shfl(h, i, 32), Wr[i], hn);
    h = silu_f(hn);
    idx += 1056;
  }
  float p0 = h * th[4288 + o];                           // final: 32->2
  float p1 = h * th[4320 + o];
  #pragma unroll
  for (int off = 16; off > 0; off >>= 1) {
    p0 += __shfl_xor(p0, off, 32);
    p1 += __shfl_xor(p1, off, 32);
  }
  if (o == 0) {
    const float mean = tanhf(p0 + th[4352]);
    float lv = p1 + th[4353];
    lv = fminf(fmaxf(lv, -4.f), 4.f);
    const float sd = __expf(0.5f * lv);
    __hip_atomic_store(&musig[2 * b], mean, __ATOMIC_RELAXED, __HIP_MEMORY_SCOPE_AGENT);
    __hip_atomic_store(&musig[2 * b + 1], sd, __ATOMIC_RELAXED, __HIP_MEMORY_SCOPE_AGENT);
    __hip_atomic_fetch_add(flag, 1u, __ATOMIC_RELEASE, __HIP_MEMORY_SCOPE_AGENT);
  }
}

// ---- 4-iter load/compute groups (explicit register double-buffer pipeline) ----
__device__ __forceinline__ void load_group(f16x8 (&B)[4][6], int g,
    const _Float16* __restrict__ ehp, const _Float16* __restrict__ elp,
    const _Float16* __restrict__ ah0p, const _Float16* __restrict__ ah1p,
    const _Float16* __restrict__ al0p, const _Float16* __restrict__ al1p) {
  #pragma unroll
  for (int i = 0; i < 4; ++i) {
    const int off = (g * 4 + i) * 512;
    B[i][0] = *(const f16x8*)(ehp + off);
    B[i][1] = *(const f16x8*)(elp + off);
    B[i][2] = *(const f16x8*)(ah0p + off);
    B[i][3] = *(const f16x8*)(ah1p + off);
    B[i][4] = *(const f16x8*)(al0p + off);
    B[i][5] = *(const f16x8*)(al1p + off);
  }
}

__device__ __forceinline__ void comp_group(f16x8 (&B)[4][6],
    f32x4& hh0, f32x4& hh1, f32x4& hl0, f32x4& hl1, f32x4& lh0, f32x4& lh1) {
  #pragma unroll
  for (int i = 0; i < 4; ++i) {
    hh0 = MFMA16(B[i][2], B[i][0], hh0, 0, 0, 0);
    hh1 = MFMA16(B[i][3], B[i][0], hh1, 0, 0, 0);
    hl0 = MFMA16(B[i][2], B[i][1], hl0, 0, 0, 0);
    hl1 = MFMA16(B[i][3], B[i][1], hl1, 0, 0, 0);
    lh0 = MFMA16(B[i][4], B[i][0], lh0, 0, 0, 0);
    lh1 = MFMA16(B[i][5], B[i][0], lh1, 0, 0, 0);
  }
}

// ---- main cooperative kernel: 64 sequential steps, 1 grid.sync/step ----
__global__ void __launch_bounds__(NTHR, 2) wsm_main(
    const float* __restrict__ xs, const float* __restrict__ noise,
    const int* __restrict__ infp,
    const _Float16* __restrict__ Ehs, const _Float16* __restrict__ Els,
    float* __restrict__ thf, _Float16* __restrict__ thh, _Float16* __restrict__ thl,
    const float* __restrict__ Bpad, float* __restrict__ musig,
    unsigned int* __restrict__ flag, float* __restrict__ outp)
{
  cooperative_groups::grid_group grid = cooperative_groups::this_grid();
  const int tid = threadIdx.x;
  const int wg = blockIdx.x;
  const int wave = tid >> 6;
  const int lane = tid & 63;
  // GEMM geometry: wave = (kchunk<<1) | psub ; 36 k-iters per chunk, stride 512 elems
  const int psub = wave & 1;
  const int kc = wave >> 1;
  const long long ebase = (((long long)(wg * 2 + psub) * KITER + kc * 36) * 64 + lane) * 8;
  const long long tbase = ((long long)(kc * 36) * 64 + lane) * 8;
  // epilogue geometry
  const int em = tid >> 4;
  const int epc0 = (tid & 15) * 2;
  const int inf_start = *infp;
  float xprev = 0.f;
  __shared__ float red[8][64][9];

  for (int t = 0; t < 64; ++t) {
    const int inb = t & 1;
    const float*    thf_in  = thf + inb * THF_STRIDE;
    float*          thf_out = thf + (inb ^ 1) * THF_STRIDE;
    const _Float16* thh_in  = thh + inb * THSWZ;
    _Float16*       thh_out = thh + (inb ^ 1) * THSWZ;
    const _Float16* thl_in  = thl + inb * THSWZ;
    _Float16*       thl_out = thl + (inb ^ 1) * THSWZ;

    // overlapped MLP(theta_t) on WGs 0..31 (wave 0, lanes<32)
    if (wg < 32 && wave == 0 && lane < 32)
      mlp_eval(wg, lane, thf_in + wg * KPAD, (float)t * (1.f / 64.f), musig, flag);

    // GEMM partial over this wave's k-chunk — explicit 4-iter double-group pipeline
    const _Float16* ehp  = Ehs + ebase;
    const _Float16* elp  = Els + ebase;
    const _Float16* ah0p = thh_in + tbase;
    const _Float16* ah1p = ah0p + HALFSTRIDE;
    const _Float16* al0p = thl_in + tbase;
    const _Float16* al1p = al0p + HALFSTRIDE;
    f32x4 z = {0.f, 0.f, 0.f, 0.f};
    f32x4 hh0 = z, hh1 = z, hl0 = z, hl1 = z, lh0 = z, lh1 = z;
    f16x8 GA[4][6], GB[4][6];
    load_group(GA, 0, ehp, elp, ah0p, ah1p, al0p, al1p);
    load_group(GB, 1, ehp, elp, ah0p, ah1p, al0p, al1p);
    comp_group(GA, hh0, hh1, hl0, hl1, lh0, lh1);
    load_group(GA, 2, ehp, elp, ah0p, ah1p, al0p, al1p);
    comp_group(GB, hh0, hh1, hl0, hl1, lh0, lh1);
    load_group(GB, 3, ehp, elp, ah0p, ah1p, al0p, al1p);
    comp_group(GA, hh0, hh1, hl0, hl1, lh0, lh1);
    load_group(GA, 4, ehp, elp, ah0p, ah1p, al0p, al1p);
    comp_group(GB, hh0, hh1, hl0, hl1, lh0, lh1);
    load_group(GB, 5, ehp, elp, ah0p, ah1p, al0p, al1p);
    comp_group(GA, hh0, hh1, hl0, hl1, lh0, lh1);
    load_group(GA, 6, ehp, elp, ah0p, ah1p, al0p, al1p);
    comp_group(GB, hh0, hh1, hl0, hl1, lh0, lh1);
    load_group(GB, 7, ehp, elp, ah0p, ah1p, al0p, al1p);
    comp_group(GA, hh0, hh1, hl0, hl1, lh0, lh1);
    load_group(GA, 8, ehp, elp, ah0p, ah1p, al0p, al1p);
    comp_group(GB, hh0, hh1, hl0, hl1, lh0, lh1);
    comp_group(GA, hh0, hh1, hl0, hl1, lh0, lh1);

    const f32x4 c0 = hh0 + hl0 + lh0;   // batch rows 0..15
    const f32x4 c1 = hh1 + hl1 + lh1;   // batch rows 16..31
    #pragma unroll
    for (int r = 0; r < 4; ++r) {
      red[wave][lane][r] = c0[r];
      red[wave][lane][4 + r] = c1[r];
    }
    __syncthreads();

    // wait musig_t (32 producers/step, monotonic counter)
    const unsigned int tgt = 32u * (unsigned)(t + 1);
    while (__hip_atomic_load(flag, __ATOMIC_ACQUIRE, __HIP_MEMORY_SCOPE_AGENT) < tgt)
      __builtin_amdgcn_s_sleep(8);

    const float mean = __hip_atomic_load(&musig[2 * em], __ATOMIC_RELAXED, __HIP_MEMORY_SCOPE_AGENT);
    const float sd   = __hip_atomic_load(&musig[2 * em + 1], __ATOMIC_RELAXED, __HIP_MEMORY_SCOPE_AGENT);
    const float xhat = fmaf(noise[t * 32 + em], sd, mean);
    const float xt   = (t < inf_start) ? xs[em * 64 + t] : xhat;
    const float dlt  = xt - xprev;
    xprev = xt;

    // epilogue: 2 elements per thread: theta_{t+1}[em][pc]
    #pragma unroll
    for (int jj = 0; jj < 2; ++jj) {
      const int pcl = epc0 + jj;
      const int pc = wg * 32 + pcl;
      const int lanei = (pcl & 15) + (((em & 15) >> 2) << 4);
      const int reg = em & 3;
      const int hf4 = (em >> 4) * 4;
      float s = 0.f;
      #pragma unroll
      for (int k2 = 0; k2 < 4; ++k2)
        s += red[k2 * 2 + (pcl >> 4)][lanei][hf4 + reg];
      const long long idx = (long long)em * KPAD + pc;
      float v = thf_in[idx] + s + dlt * Bpad[pc];
      v = fminf(fmaxf(v, -1.f), 1.f);
      thf_out[idx] = v;
      const _Float16 hv = (_Float16)v;
      const _Float16 lvv = (_Float16)(v - (float)hv);
      // swizzled store: [half][ki][lane][j]
      const int ki_e = pc >> 5;
      const int sub_e = (pc >> 3) & 3;
      const int j_e = pc & 7;
      const int lane_e = (em & 15) + (sub_e << 4);
      const long long sidx = (((long long)(em >> 4) * KITER + ki_e) * 64 + lane_e) * 8 + j_e;
      thh_out[sidx] = hv;
      thl_out[sidx] = lvv;
    }

    if (wg == 0 && tid < 32) {
      outp[tid * 64 + t] = __hip_atomic_load(&musig[2 * tid], __ATOMIC_RELAXED, __HIP_MEMORY_SCOPE_AGENT);
      outp[32 * 64 + tid * 64 + t] = __hip_atomic_load(&musig[2 * tid + 1], __ATOMIC_RELAXED, __HIP_MEMORY_SCOPE_AGENT);
    }

    grid.sync();
  }
}

extern "C" void kernel_launch(void* const* d_in, const int* in_sizes, int n_in,
                              void* d_out, int out_size, void* d_ws, size_t ws_size,
                              hipStream_t stream) {
  const float* xs  = (const float*)d_in[0];
  const float* noise = (const float*)d_in[1];
  const float* th0 = (const float*)d_in[2];
  const float* A   = (const float*)d_in[3];
  const float* Bv  = (const float*)d_in[4];
  const int* infs  = (const int*)d_in[5];

  char* ws = (char*)d_ws;
  size_t off = 0;
  auto carve = [&](size_t bytes) -> void* {
    off = (off + 255) & ~(size_t)255;
    void* p = ws + off;
    off += bytes;
    return p;
  };
  _Float16* Ehs = (_Float16*)carve((size_t)NPT * KITER * 512 * sizeof(_Float16));
  _Float16* Els = (_Float16*)carve((size_t)NPT * KITER * 512 * sizeof(_Float16));
  float*    thf = (float*)carve((size_t)2 * THF_STRIDE * sizeof(float));
  _Float16* thh = (_Float16*)carve((size_t)2 * THSWZ * sizeof(_Float16));
  _Float16* thl = (_Float16*)carve((size_t)2 * THSWZ * sizeof(_Float16));
  float*   Bpad = (float*)carve((size_t)PPAD * sizeof(float));
  float*  musig = (float*)carve((size_t)64 * sizeof(float));
  unsigned int* flag = (unsigned int*)carve(sizeof(unsigned int));
  float* outp = (float*)d_out;

  wsm_prep<<<dim3(1024), dim3(256), 0, stream>>>(A, Bv, th0, Ehs, Els, thf, thh, thl, Bpad, flag);

  void* args[] = {(void*)&xs, (void*)&noise, (void*)&infs, (void*)&Ehs, (void*)&Els,
                  (void*)&thf, (void*)&thh, (void*)&thl, (void*)&Bpad,
                  (void*)&musig, (void*)&flag, (void*)&outp};
  hipLaunchCooperativeKernel((const void*)wsm_main, dim3(NWG), dim3(NTHR), args, 0, stream);
}